// Round 1
// baseline (153.025 us; speedup 1.0000x reference)
//
#include <hip/hip_runtime.h>
#include <hip/hip_bf16.h>
#include <stdint.h>

typedef __bf16 bf16x8 __attribute__((ext_vector_type(8)));
typedef __bf16 bf16x2 __attribute__((ext_vector_type(2)));
typedef float f32x4 __attribute__((ext_vector_type(4)));

#define D 128
#define BQ 64
#define BK 64

// LDS strides (padded against bank conflicts)
#define KT_STRIDE 136   // bf16 units per K-tile row (128 + 8)
#define VP_STRIDE 132   // dwords per pair-packed V row (128 + 4) -> 4hi groups shift 16 banks
#define PT_STRIDE 72    // bf16 units per P transit row (64 + 8)

__device__ __forceinline__ uint32_t pack_bf16(float a, float b) {
    bf16x2 v; v[0] = (__bf16)a; v[1] = (__bf16)b;
    return __builtin_bit_cast(uint32_t, v);
}
__device__ __forceinline__ uint16_t to_bf16_bits(float a) {
    __bf16 h = (__bf16)a;
    return __builtin_bit_cast(uint16_t, h);
}

__global__ __launch_bounds__(256, 2) void la_fwd(
    const float* __restrict__ Q, const float* __restrict__ K,
    const float* __restrict__ V, float* __restrict__ O, int n, int nqt)
{
    __shared__ __align__(16) uint16_t Kt[BK * KT_STRIDE];        // 17408 B
    __shared__ __align__(16) uint32_t VP[(BK / 2) * VP_STRIDE];  // 16896 B
    __shared__ __align__(16) uint16_t Pt[4][16 * PT_STRIDE];     //  9216 B

    const int tid  = threadIdx.x;
    const int wave = tid >> 6;
    const int lane = tid & 63;
    const int m    = lane & 15;   // fragment row/col
    const int hi   = lane >> 4;   // 0..3

    const int qt = (nqt - 1) - blockIdx.x;  // big (diagonal) tiles dispatch first
    const int bh = blockIdx.y;              // 0..15
    const int h  = bh & 7;
    const float slope = exp2f(-(float)(h + 1));

    const size_t base = (size_t)bh * n * D;
    const float* Qb = Q + base;
    const float* Kb = K + base;
    const float* Vb = V + base;
    float*       Ob = O + base;

    const int qrow0 = qt * BQ + wave * 16;  // this wave's q-row base

    // ---- Q fragments (A-layout: row=m, k=32*s+8*hi+e), held in registers ----
    bf16x8 qf[4];
    {
        const float* qp = Qb + (size_t)(qrow0 + m) * D + hi * 8;
        #pragma unroll
        for (int s = 0; s < 4; ++s) {
            float4 a = *(const float4*)(qp + s * 32);
            float4 b = *(const float4*)(qp + s * 32 + 4);
            bf16x8 f;
            f[0] = (__bf16)a.x; f[1] = (__bf16)a.y; f[2] = (__bf16)a.z; f[3] = (__bf16)a.w;
            f[4] = (__bf16)b.x; f[5] = (__bf16)b.y; f[6] = (__bf16)b.z; f[7] = (__bf16)b.w;
            qf[s] = f;
        }
    }

    // ---- per-lane decay factors: decay = C_tile * ei[r] * ej[jf] ----
    float ei[4], ej[4];
    #pragma unroll
    for (int r = 0; r < 4; ++r)  ei[r]  = __expf(-slope * (float)(4 * hi + r));
    #pragma unroll
    for (int jf = 0; jf < 4; ++jf) ej[jf] = __expf(slope * (float)(jf * 16 + m));

    f32x4 acc[8];
    #pragma unroll
    for (int i = 0; i < 8; ++i) acc[i] = (f32x4){0.f, 0.f, 0.f, 0.f};

    uint16_t* PtW = &Pt[wave][0];

    for (int jt = 0; jt <= qt; ++jt) {
        __syncthreads();  // previous iteration's LDS reads done

        // ---- stage K tile: bf16 row-major [64][KT_STRIDE] ----
        {
            const float* src = Kb + (size_t)jt * BK * D;
            #pragma unroll
            for (int i = 0; i < 8; ++i) {
                int idx = tid + 256 * i;       // float4 index in 64x128 tile
                int row = idx >> 5;
                int c4  = idx & 31;
                float4 a = *(const float4*)(src + (size_t)idx * 4);
                uint2 w;
                w.x = pack_bf16(a.x, a.y);
                w.y = pack_bf16(a.z, a.w);
                *(uint2*)&Kt[row * KT_STRIDE + c4 * 4] = w;
            }
        }
        // ---- stage V tile: pair-packed VP[jp][d] = (V[2jp][d], V[2jp+1][d]) ----
        {
            const float* src = Vb + (size_t)jt * BK * D;
            #pragma unroll
            for (int i = 0; i < 4; ++i) {
                int jp = (tid >> 5) + 8 * i;
                int c4 = tid & 31;
                const float* p0 = src + (size_t)(2 * jp) * D + c4 * 4;
                float4 a = *(const float4*)p0;
                float4 b = *(const float4*)(p0 + D);
                uint4 w;
                w.x = pack_bf16(a.x, b.x);
                w.y = pack_bf16(a.y, b.y);
                w.z = pack_bf16(a.z, b.z);
                w.w = pack_bf16(a.w, b.w);
                *(uint4*)&VP[jp * VP_STRIDE + c4 * 4] = w;
            }
        }
        __syncthreads();  // staging visible to all waves

        // ---- S = Q K^T (16 x 64 per wave), decay+mask, transit to LDS ----
        const float Cs = __expf(-slope * (float)(qrow0 - jt * BK));
        float fi[4];
        #pragma unroll
        for (int r = 0; r < 4; ++r) fi[r] = Cs * ei[r];

        const bool diag = (jt == qt);
        #pragma unroll
        for (int jf = 0; jf < 4; ++jf) {
            f32x4 s = (f32x4){0.f, 0.f, 0.f, 0.f};
            #pragma unroll
            for (int ss = 0; ss < 4; ++ss) {
                bf16x8 kf = *(const bf16x8*)&Kt[(jf * 16 + m) * KT_STRIDE + ss * 32 + hi * 8];
                s = __builtin_amdgcn_mfma_f32_16x16x32_bf16(qf[ss], kf, s, 0, 0, 0);
            }
            #pragma unroll
            for (int r = 0; r < 4; ++r) {
                float val = s[r] * (fi[r] * ej[jf]);
                if (diag) {
                    int iloc = (qrow0 - jt * BK) + 4 * hi + r;
                    int jloc = jf * 16 + m;
                    if (iloc < jloc) val = 0.f;
                }
                // D-frag (row=4hi+r, col=jf*16+m) -> P transit
                PtW[(4 * hi + r) * PT_STRIDE + jf * 16 + m] = to_bf16_bits(val);
            }
        }

        // ---- O += P V ----
        // A-frag: P[row=m][k=32*s+8*hi+e]
        bf16x8 pa0 = *(const bf16x8*)&PtW[m * PT_STRIDE + hi * 8];
        bf16x8 pa1 = *(const bf16x8*)&PtW[m * PT_STRIDE + 32 + hi * 8];
        #pragma unroll
        for (int d0 = 0; d0 < 8; ++d0) {
            {
                int r0 = (4 * hi) * VP_STRIDE + d0 * 16 + m;  // s=0: jp rows 4hi+e2
                uint4 bw;
                bw.x = VP[r0];
                bw.y = VP[r0 + VP_STRIDE];
                bw.z = VP[r0 + 2 * VP_STRIDE];
                bw.w = VP[r0 + 3 * VP_STRIDE];
                acc[d0] = __builtin_amdgcn_mfma_f32_16x16x32_bf16(
                    pa0, __builtin_bit_cast(bf16x8, bw), acc[d0], 0, 0, 0);
            }
            {
                int r1 = (16 + 4 * hi) * VP_STRIDE + d0 * 16 + m;  // s=1
                uint4 bw;
                bw.x = VP[r1];
                bw.y = VP[r1 + VP_STRIDE];
                bw.z = VP[r1 + 2 * VP_STRIDE];
                bw.w = VP[r1 + 3 * VP_STRIDE];
                acc[d0] = __builtin_amdgcn_mfma_f32_16x16x32_bf16(
                    pa1, __builtin_bit_cast(bf16x8, bw), acc[d0], 0, 0, 0);
            }
        }
    }

    // ---- write O: D-frag row=4hi+r, col=d0*16+m ----
    #pragma unroll
    for (int d0 = 0; d0 < 8; ++d0) {
        #pragma unroll
        for (int r = 0; r < 4; ++r) {
            Ob[(size_t)(qrow0 + 4 * hi + r) * D + d0 * 16 + m] = acc[d0][r];
        }
    }
}

extern "C" void kernel_launch(void* const* d_in, const int* in_sizes, int n_in,
                              void* d_out, int out_size, void* d_ws, size_t ws_size,
                              hipStream_t stream) {
    const float* q = (const float*)d_in[0];
    const float* k = (const float*)d_in[1];
    const float* v = (const float*)d_in[2];
    float* out = (float*)d_out;
    int total = in_sizes[0];          // b*h*n*d = 16*n*128
    int n = total / (16 * 128);
    int nqt = n / BQ;
    dim3 grid(nqt, 16);
    la_fwd<<<grid, 256, 0, stream>>>(q, k, v, out, n, nqt);
}

// Round 2
// 65.609 us; speedup vs baseline: 2.3324x; 2.3324x over previous
//
#include <hip/hip_runtime.h>
#include <hip/hip_bf16.h>
#include <stdint.h>

typedef __bf16 bf16x8 __attribute__((ext_vector_type(8)));
typedef __bf16 bf16x2 __attribute__((ext_vector_type(2)));
typedef float f32x4 __attribute__((ext_vector_type(4)));

#define D 128
#define BQ 64
#define BK 64
#define NCH 16   // K-tiles per chunk-block

// LDS strides (padded against bank conflicts)
#define KT_STRIDE 136   // bf16 units per K-tile row (128 + 8)
#define VP_STRIDE 132   // dwords per pair-packed V row (128 + 4)
#define PT_STRIDE 72    // bf16 units per P transit row (64 + 8)

__device__ __forceinline__ uint32_t pack_bf16(float a, float b) {
    bf16x2 v; v[0] = (__bf16)a; v[1] = (__bf16)b;
    return __builtin_bit_cast(uint32_t, v);
}
__device__ __forceinline__ uint16_t to_bf16_bits(float a) {
    __bf16 h = (__bf16)a;
    return __builtin_bit_cast(uint16_t, h);
}

__global__ __launch_bounds__(256, 2) void la_fwd(
    const float* __restrict__ Q, const float* __restrict__ K,
    const float* __restrict__ V, float* __restrict__ O, int n, int nqt)
{
    __shared__ __align__(16) uint16_t Kt[BK * KT_STRIDE];        // 17408 B
    __shared__ __align__(16) uint32_t VP[(BK / 2) * VP_STRIDE];  // 16896 B
    __shared__ __align__(16) uint16_t Pt[4][16 * PT_STRIDE];     //  9216 B

    const int tid  = threadIdx.x;
    const int wave = tid >> 6;
    const int lane = tid & 63;
    const int m    = lane & 15;
    const int hi   = lane >> 4;

    // ---- block -> (qt, j0, j1, multi) ; big blocks dispatch first ----
    const int E = (nqt > NCH) ? (nqt - NCH) : 0;  // q-tiles split into 2 chunks
    const int x = blockIdx.x;
    int qt, j0, j1;
    bool multi;
    if (x < 2 * E) {
        qt = (nqt - 1) - (x >> 1);
        multi = true;
        if (x & 1) { j0 = NCH; j1 = qt + 1; }
        else       { j0 = 0;   j1 = NCH;    }
    } else {
        int SC = (nqt < NCH) ? nqt : NCH;
        qt = (SC - 1) - (x - 2 * E);
        multi = false;
        j0 = 0; j1 = qt + 1;
    }

    const int bh = blockIdx.y;
    const int h  = bh & 7;
    const float slope = exp2f(-(float)(h + 1));

    // ---- decay banding: tiles with slope*dist > 9 contribute < ~0.1 abs ----
    // keep qt - jt <= band-1  <=>  jt >= qt+1-band
    const int band = ((9 << (h + 1)) + 63) / 64 + 1;
    {
        int jlo = qt + 1 - band;
        if (jlo > j0) j0 = jlo;
    }
    if (j0 >= j1) return;  // empty chunk (multi-c0 fully banded out); memset covers O

    const size_t base = (size_t)bh * n * D;
    const float* Qb = Q + base;
    const float* Kb = K + base;
    const float* Vb = V + base;
    float*       Ob = O + base;

    const int qrow0 = qt * BQ + wave * 16;

    // ---- Q fragments (A-layout: row=m, k=32*s+8*hi+e) ----
    bf16x8 qf[4];
    {
        const float* qp = Qb + (size_t)(qrow0 + m) * D + hi * 8;
        #pragma unroll
        for (int s = 0; s < 4; ++s) {
            float4 a = *(const float4*)(qp + s * 32);
            float4 b = *(const float4*)(qp + s * 32 + 4);
            bf16x8 f;
            f[0] = (__bf16)a.x; f[1] = (__bf16)a.y; f[2] = (__bf16)a.z; f[3] = (__bf16)a.w;
            f[4] = (__bf16)b.x; f[5] = (__bf16)b.y; f[6] = (__bf16)b.z; f[7] = (__bf16)b.w;
            qf[s] = f;
        }
    }

    float ei[4], ej[4];
    #pragma unroll
    for (int r = 0; r < 4; ++r)   ei[r] = __expf(-slope * (float)(4 * hi + r));
    #pragma unroll
    for (int jf = 0; jf < 4; ++jf) ej[jf] = __expf(slope * (float)(jf * 16 + m));

    f32x4 acc[8];
    #pragma unroll
    for (int i = 0; i < 8; ++i) acc[i] = (f32x4){0.f, 0.f, 0.f, 0.f};

    uint16_t* PtW = &Pt[wave][0];

    // ---- staging helpers: load to regs (prefetch), write regs -> LDS ----
    float4 ka[8], va[8], kb[8], vb[8];

    auto stage_load = [&](int jt, float4* kr, float4* vr) {
        const float* ks = Kb + (size_t)jt * BK * D;
        #pragma unroll
        for (int i = 0; i < 8; ++i)
            kr[i] = *(const float4*)(ks + (size_t)(tid + 256 * i) * 4);
        const float* vs = Vb + (size_t)jt * BK * D;
        #pragma unroll
        for (int i = 0; i < 4; ++i) {
            int jp = (tid >> 5) + 8 * i;
            int c4 = tid & 31;
            const float* p0 = vs + (size_t)(2 * jp) * D + c4 * 4;
            vr[2 * i]     = *(const float4*)p0;
            vr[2 * i + 1] = *(const float4*)(p0 + D);
        }
    };
    auto stage_write = [&](const float4* kr, const float4* vr) {
        #pragma unroll
        for (int i = 0; i < 8; ++i) {
            int idx = tid + 256 * i;
            int row = idx >> 5, c4 = idx & 31;
            uint2 w;
            w.x = pack_bf16(kr[i].x, kr[i].y);
            w.y = pack_bf16(kr[i].z, kr[i].w);
            *(uint2*)&Kt[row * KT_STRIDE + c4 * 4] = w;
        }
        #pragma unroll
        for (int i = 0; i < 4; ++i) {
            int jp = (tid >> 5) + 8 * i, c4 = tid & 31;
            float4 a = vr[2 * i], b = vr[2 * i + 1];
            uint4 w;
            w.x = pack_bf16(a.x, b.x);
            w.y = pack_bf16(a.y, b.y);
            w.z = pack_bf16(a.z, b.z);
            w.w = pack_bf16(a.w, b.w);
            *(uint4*)&VP[jp * VP_STRIDE + c4 * 4] = w;
        }
    };

    auto compute = [&](int jt) {
        const float Cs = __expf(-slope * (float)(qrow0 - jt * BK));
        float fi[4];
        #pragma unroll
        for (int r = 0; r < 4; ++r) fi[r] = Cs * ei[r];

        const bool diag = (jt == qt);
        #pragma unroll
        for (int jf = 0; jf < 4; ++jf) {
            f32x4 s = (f32x4){0.f, 0.f, 0.f, 0.f};
            #pragma unroll
            for (int ss = 0; ss < 4; ++ss) {
                bf16x8 kf = *(const bf16x8*)&Kt[(jf * 16 + m) * KT_STRIDE + ss * 32 + hi * 8];
                s = __builtin_amdgcn_mfma_f32_16x16x32_bf16(qf[ss], kf, s, 0, 0, 0);
            }
            #pragma unroll
            for (int r = 0; r < 4; ++r) {
                float val = s[r] * (fi[r] * ej[jf]);
                if (diag) {
                    int iloc = (qrow0 - jt * BK) + 4 * hi + r;
                    int jloc = jf * 16 + m;
                    if (iloc < jloc) val = 0.f;
                }
                PtW[(4 * hi + r) * PT_STRIDE + jf * 16 + m] = to_bf16_bits(val);
            }
        }

        bf16x8 pa0 = *(const bf16x8*)&PtW[m * PT_STRIDE + hi * 8];
        bf16x8 pa1 = *(const bf16x8*)&PtW[m * PT_STRIDE + 32 + hi * 8];
        #pragma unroll
        for (int d0 = 0; d0 < 8; ++d0) {
            {
                int r0 = (4 * hi) * VP_STRIDE + d0 * 16 + m;
                uint4 bw;
                bw.x = VP[r0];
                bw.y = VP[r0 + VP_STRIDE];
                bw.z = VP[r0 + 2 * VP_STRIDE];
                bw.w = VP[r0 + 3 * VP_STRIDE];
                acc[d0] = __builtin_amdgcn_mfma_f32_16x16x32_bf16(
                    pa0, __builtin_bit_cast(bf16x8, bw), acc[d0], 0, 0, 0);
            }
            {
                int r1 = (16 + 4 * hi) * VP_STRIDE + d0 * 16 + m;
                uint4 bw;
                bw.x = VP[r1];
                bw.y = VP[r1 + VP_STRIDE];
                bw.z = VP[r1 + 2 * VP_STRIDE];
                bw.w = VP[r1 + 3 * VP_STRIDE];
                acc[d0] = __builtin_amdgcn_mfma_f32_16x16x32_bf16(
                    pa1, __builtin_bit_cast(bf16x8, bw), acc[d0], 0, 0, 0);
            }
        }
    };

    auto iter = [&](int jt, float4* ck, float4* cv, float4* nk, float4* nv) {
        __syncthreads();                       // prev iter's LDS reads done
        stage_write(ck, cv);
        if (jt + 1 < j1) stage_load(jt + 1, nk, nv);  // prefetch under compute
        __syncthreads();                       // staging visible
        compute(jt);
    };

    // ---- main loop: register double-buffered, parity-unrolled ----
    stage_load(j0, ka, va);
    int jt = j0;
    while (jt < j1) {
        iter(jt, ka, va, kb, vb); ++jt;
        if (jt < j1) { iter(jt, kb, vb, ka, va); ++jt; }
    }

    // ---- epilogue: plain store (single writer) or atomic add (split) ----
    if (multi) {
        #pragma unroll
        for (int d0 = 0; d0 < 8; ++d0) {
            #pragma unroll
            for (int r = 0; r < 4; ++r) {
                unsafeAtomicAdd(&Ob[(size_t)(qrow0 + 4 * hi + r) * D + d0 * 16 + m],
                                acc[d0][r]);
            }
        }
    } else {
        #pragma unroll
        for (int d0 = 0; d0 < 8; ++d0) {
            #pragma unroll
            for (int r = 0; r < 4; ++r) {
                Ob[(size_t)(qrow0 + 4 * hi + r) * D + d0 * 16 + m] = acc[d0][r];
            }
        }
    }
}

extern "C" void kernel_launch(void* const* d_in, const int* in_sizes, int n_in,
                              void* d_out, int out_size, void* d_ws, size_t ws_size,
                              hipStream_t stream) {
    const float* q = (const float*)d_in[0];
    const float* k = (const float*)d_in[1];
    const float* v = (const float*)d_in[2];
    float* out = (float*)d_out;
    int total = in_sizes[0];          // b*h*n*d = 16*n*128
    int n = total / (16 * 128);
    int nqt = n / BQ;
    int E = (nqt > NCH) ? (nqt - NCH) : 0;
    int gx = 2 * E + ((nqt < NCH) ? nqt : NCH);
    hipMemsetAsync(d_out, 0, (size_t)out_size * sizeof(float), stream);
    dim3 grid(gx, 16);
    la_fwd<<<grid, 256, 0, stream>>>(q, k, v, out, n, nqt);
}